// Round 13
// baseline (155.139 us; speedup 1.0000x reference)
//
#include <hip/hip_runtime.h>
#include <stdint.h>

// Multi-head Hyena conv, MFMA flash-attention form, round 23:
//   S^T[m][l] = sum_d1 v[d1,m]*x1[d1,l]       mfma 16x16x16 (K=8 valid)
//   P[l][m]   = S * k[l-m]   (sliding f32x4 gate window, zero => causal)
//   O^T[d2][l] += x2 . P^T                    mfma 16x16x32 (full K=32)
// Round-23: PROLOGUE-BUILT FLAT GATE TABLE. r22 (barrier-free) regressed
// -6%: doubled staging VALU + scalar gate reads; cost model confirmed 5x:
// body VALU = wall 1:1. r20 stands (70.9us). Only remaining pure DELETION:
// the per-chunk gwin rebuild (kg global prefetch + branch + LDS write,
// ~15-20 inst/chunk/thread + 4 regs). Gate entry is a pure function of
// i = l0b-s0-127+e with block-global range [-60, nk-1] -> build ONCE as
// flat gwin2[KOFF+nk] float4 (KOFF=64; verified idx_min=4 over all
// (t,wseg,c)), read-only after. Loop reads stay 2x ds_read_b128 (same
// addressing/conflict profile, base gb = KOFF+l0b-s0-127+ebase).
// LDS 25.5->50.5KB -> LDS-max 3 blocks/CU; measured occupancy has been
// ~38% (=3 blocks) across ALL clean configs r13-r22, so cap should be
// non-binding. Tripwires: occ<33% or dur>74 -> LDS cap bit, revert;
// WRITE>25MB = spill -> revert. Clean-but-neutral => structural plateau.
// Carried (r20): (256,4), 16x16x16 S, dbuf vT/x2T + single barrier per
// chunk, write-late/issue-early v/x2 stage regs, carried gate file,
// rolling loop, v_pk_mul+v_perm gating.
// Shapes fixed by setup: B=2, D=1024, L=2048, NH=8, H=128.

typedef __attribute__((ext_vector_type(8))) short bf16x8;
typedef __attribute__((ext_vector_type(4))) short bf16x4;
typedef __attribute__((ext_vector_type(4))) float f32x4;
typedef __attribute__((ext_vector_type(2))) float f32x2;

#define NHd  8
#define SC   128     // m superchunk staged in LDS
#define KOFF 64      // gwin2 pad: lowest read idx = 4 (proof in header)

static __device__ __forceinline__ uint32_t pkbf(float a, float b) {
    // RNE-ish pack {bf16(a) lo, bf16(b) hi}; +0x8000 rounds (ties away)
    const uint32_t ua = __float_as_uint(a) + 0x8000u;
    const uint32_t ub = __float_as_uint(b) + 0x8000u;
    return __builtin_amdgcn_perm(ub, ua, 0x07060302u);
}

static __device__ __forceinline__ uint32_t pktr(f32x2 p) {
    // truncation pack: upper 16 bits of each f32 -> {lo,hi} bf16 (1 v_perm)
    union { f32x2 f; uint32_t u[2]; } c; c.f = p;
    return __builtin_amdgcn_perm(c.u[1], c.u[0], 0x07060302u);
}

// gate two S values by two k values: v_pk_mul_f32 + v_perm (2 inst)
static __device__ __forceinline__ uint32_t gmul2(f32x2 s, f32x2 g) {
    return pktr(s * g);
}

// S-MFMA: 16x16x16 bf16 (K=8 valid). Same C layout as 16x16x32 family.
static __device__ __forceinline__ f32x4 mfmaS(bf16x4 a, bf16x4 b, f32x4 c) {
#if __has_builtin(__builtin_amdgcn_mfma_f32_16x16x16bf16_1k)
    return __builtin_amdgcn_mfma_f32_16x16x16bf16_1k(a, b, c, 0, 0, 0);
#else
    f32x4 d;
    asm("v_mfma_f32_16x16x16_bf16 %0, %1, %2, %3"
        : "=v"(d) : "v"(a), "v"(b), "v"(c));
    return d;
#endif
}

union U8 { uint32_t u[4]; bf16x8 v; uint4 q; };
union U4 { uint32_t u[2]; bf16x4 v; };

__global__ __launch_bounds__(256, 4) void hyena_mfma23_kernel(
    const float* __restrict__ v, const float* __restrict__ kf,
    const float* __restrict__ bias, const float* __restrict__ x1,
    const float* __restrict__ x2, float* __restrict__ out,
    int B, int H, int L)
{
    __shared__ __align__(16) float4 gwin2[KOFF + 2048];  // flat gate table
    __shared__ __align__(16) ushort vT[2][2][SC][NHd];   // [buf][b][m][d1]
    __shared__ __align__(16) ushort x2T[2][2][NHd][136]; // [buf][b][d2][pi(m)]
    __shared__ float sbuf[2][128];                       // skip gate per (b,l)

    const int tid  = threadIdx.x;
    const int h    = blockIdx.x;
    const int l0b  = ((int)gridDim.y - 1 - (int)blockIdx.y) * 128; // big-l first
    const int nk   = l0b + 128;

    const int lane = tid & 63, wv = tid >> 6;
    const int lq   = lane & 15, quad = lane >> 4;
    const int wb   = wv & 1;                // batch handled by this wave
    const int wseg = wv >> 1;               // which 64-l half of the block
    const int wl0  = l0b + wseg * 64;       // wave's 64-l range start
    const int baseb = (wb * H + h) * NHd * L;

    // ---------- fixed staging coordinates ----------
    const int sb_b   = tid >> 7, sb_row = tid & 127;
    const int sb_bs  = (sb_b * H + h) * NHd * L;
    const float* vp0 = v + sb_bs + sb_row;
    const int sb_d2  = sb_row >> 4, sb_ms = (sb_row & 15) * 8;
    const int sb_G   = sb_ms & ~31;                 // 32-group base
    const int sb_o   = sb_ms & 31;                  // 0,8,16,24
    const int sb_pa  = ((sb_o >> 2) & 3) * 8 + (sb_o >> 4) * 4;
    const float* xp0 = x2 + sb_bs + sb_d2 * L + sb_ms;
    const float* kp  = kf + h * L;

    // ---------- async stage registers (one chunk in flight) ----------
    float  fv0, fv1, fv2, fv3, fv4, fv5, fv6, fv7;  // v column, 8 x d1
    float4 q0, q1;                                   // x2 8-run

    auto issue_stage = [&](int s0) {
        const float* vp = vp0 + s0;
        fv0 = vp[0 * L]; fv1 = vp[1 * L]; fv2 = vp[2 * L]; fv3 = vp[3 * L];
        fv4 = vp[4 * L]; fv5 = vp[5 * L]; fv6 = vp[6 * L]; fv7 = vp[7 * L];
        q0 = *(const float4*)(xp0 + s0);
        q1 = *(const float4*)(xp0 + s0 + 4);
    };

    // ---------- prologue ----------
    issue_stage(0);   // chunk-0 loads fly under table/xf/sbuf build below

    // Flat gate table, built once (read-only after first chunk barrier):
    // gwin2[idx] = {k[i],k[i-1],k[i-2],k[i-3]}, i = idx-KOFF, k[<0] = 0.
    // Only entries idx < KOFF+nk are ever read (max i = nk-1).
    for (int idx = tid; idx < KOFF + nk; idx += 256) {
        const int i = idx - KOFF;
        float4 w = {0.f, 0.f, 0.f, 0.f};
        if (i >= 3) {
            w.x = kp[i]; w.y = kp[i - 1]; w.z = kp[i - 2]; w.w = kp[i - 3];
        } else if (i >= 0) {
            w.x = kp[i];
            if (i >= 1) w.y = kp[i - 1];
            if (i >= 2) w.z = kp[i - 2];
        }
        gwin2[idx] = w;
    }

    // xf fragments (S-MFMA B operand, 16x16x16: k=4*(lane>>4)+i) for 4
    // l-subtiles. Quads 0-1 carry d1 = 4*quad+t; quads 2-3 zero.
    bf16x4 xf[4] = {};
    if (quad < 2) {
#pragma unroll
        for (int j = 0; j < 4; ++j) {
            float a0[4];
#pragma unroll
            for (int t = 0; t < 4; ++t)
                a0[t] = x1[baseb + (4 * quad + t) * L + wl0 + 16 * j + lq];
            U4 u0;
            u0.u[0] = pkbf(a0[0], a0[1]);
            u0.u[1] = pkbf(a0[2], a0[3]);
            xf[j] = u0.v;
        }
    }

    // skip-term gate, both b, 128 l (all 256 threads)
    {
        const int bb = tid >> 7, l = tid & 127;
        const int bs = (bb * H + h) * NHd * L;
        float s = 0.f;
#pragma unroll
        for (int d1 = 0; d1 < NHd; ++d1)
            s += bias[h * NHd + d1] * x1[bs + d1 * L + l0b + l]
                                    * v [bs + d1 * L + l0b + l];
        sbuf[bb][l] = s;
    }

    f32x4 acc[4];
#pragma unroll
    for (int j = 0; j < 4; ++j) acc[j] = (f32x4){0.f, 0.f, 0.f, 0.f};

    const int wlmax = wl0 + 63;
    // gate window coordinate (s0-independent): e = ebase - c
    const int ebase = 127 + wseg * 64 + lq - 4 * quad;
    const int gb0   = KOFF + l0b - 127 + ebase;   // table idx of g1 @ s0=0,c=0

    bool gfirst = true;
    float4 g0, g1, g2, g3, g4;   // 5-deep gate file; carries across s0 too

    for (int s0 = 0, n = 0; s0 < nk; s0 += SC, ++n) {
        const int p = n & 1;

        // ---- write-late: stage regs (chunk n's data) -> buf p ----
        // WAR-safe: all waves passed barrier n-1, which follows their
        // compute n-2 (the last reader of buf p). Concurrent compute n-1
        // reads buf p^1. gwin2/sbuf are read-only after barrier 0.
        *(uint4*)&vT[p][sb_b][sb_row][0] = make_uint4(
            pkbf(fv0, fv1), pkbf(fv2, fv3), pkbf(fv4, fv5), pkbf(fv6, fv7));
        *(uint2*)&x2T[p][sb_b][sb_d2][sb_G + sb_pa] =
            make_uint2(pkbf(q0.x, q0.y), pkbf(q0.z, q0.w));
        *(uint2*)&x2T[p][sb_b][sb_d2][sb_G + sb_pa + 8] =
            make_uint2(pkbf(q1.x, q1.y), pkbf(q1.z, q1.w));

        // ---- issue-early: next chunk's global loads fly under compute ----
        if (s0 + SC < nk) issue_stage(s0 + SC);

        // ---- single barrier: staging visible; global loads NOT drained ----
        asm volatile("s_waitcnt lgkmcnt(0)" ::: "memory");
        __builtin_amdgcn_s_barrier();

        const int gb = gb0 - s0;   // table idx of g1 at c=0 this chunk

        // wave-uniform trip count, multiple of 32 (wseg0: 64 at diagonal)
        const int cmax = min(SC, wlmax - s0 + 1);
        for (int c = 0; c < cmax; c += 32) {
            // ---- loads first (independent) ----
            // A frag (16x16x16): row=lane&15, k=4*(lane>>4)+i -> quads 0-1
            // read d1 = 4*quad..4*quad+3 (8B each); quads 2-3 zero.
            bf16x4 av0 = {}, av1 = {};
            if (quad < 2) {
                av0 = *(const bf16x4*)&vT[p][wb][c + lq][quad * 4];
                av1 = *(const bf16x4*)&vT[p][wb][c + 16 + lq][quad * 4];
            }
            // gate file: subtile j: lo = g(idx+16j), hi = g(idx+16j-16).
            // Table is read-only => rotation identical to r20's semantics.
            if (gfirst) {
                g4 = *(const float4*)&gwin2[gb + 48];
                g3 = *(const float4*)&gwin2[gb + 32];
                g2 = *(const float4*)&gwin2[gb + 16];
                gfirst = false;
            } else { g4 = g2; g3 = g1; g2 = g0; }
            g1 = *(const float4*)&gwin2[gb - c];
            g0 = *(const float4*)&gwin2[gb - c - 16];
            const bf16x8 ax = *(const bf16x8*)&x2T[p][wb][lq & 7][c + 8 * quad];

            const f32x4 Z = {0.f, 0.f, 0.f, 0.f};
            // ---- subtile pair 0,1 ----
            {
                const f32x4 Sa0 = mfmaS(av0, xf[0], Z);
                const f32x4 Sa1 = mfmaS(av1, xf[0], Z);
                const f32x4 Sb0 = mfmaS(av0, xf[1], Z);
                const f32x4 Sb1 = mfmaS(av1, xf[1], Z);
                U8 p2;
                p2.u[0] = gmul2((f32x2){Sa0[0], Sa0[1]}, (f32x2){g1.x, g1.y});
                p2.u[1] = gmul2((f32x2){Sa0[2], Sa0[3]}, (f32x2){g1.z, g1.w});
                p2.u[2] = gmul2((f32x2){Sa1[0], Sa1[1]}, (f32x2){g0.x, g0.y});
                p2.u[3] = gmul2((f32x2){Sa1[2], Sa1[3]}, (f32x2){g0.z, g0.w});
                acc[0] = __builtin_amdgcn_mfma_f32_16x16x32_bf16(ax, p2.v, acc[0], 0, 0, 0);
                p2.u[0] = gmul2((f32x2){Sb0[0], Sb0[1]}, (f32x2){g2.x, g2.y});
                p2.u[1] = gmul2((f32x2){Sb0[2], Sb0[3]}, (f32x2){g2.z, g2.w});
                p2.u[2] = gmul2((f32x2){Sb1[0], Sb1[1]}, (f32x2){g1.x, g1.y});
                p2.u[3] = gmul2((f32x2){Sb1[2], Sb1[3]}, (f32x2){g1.z, g1.w});
                acc[1] = __builtin_amdgcn_mfma_f32_16x16x32_bf16(ax, p2.v, acc[1], 0, 0, 0);
            }
            // ---- subtile pair 2,3 ----
            {
                const f32x4 Sc0 = mfmaS(av0, xf[2], Z);
                const f32x4 Sc1 = mfmaS(av1, xf[2], Z);
                const f32x4 Sd0 = mfmaS(av0, xf[3], Z);
                const f32x4 Sd1 = mfmaS(av1, xf[3], Z);
                U8 p2;
                p2.u[0] = gmul2((f32x2){Sc0[0], Sc0[1]}, (f32x2){g3.x, g3.y});
                p2.u[1] = gmul2((f32x2){Sc0[2], Sc0[3]}, (f32x2){g3.z, g3.w});
                p2.u[2] = gmul2((f32x2){Sc1[0], Sc1[1]}, (f32x2){g2.x, g2.y});
                p2.u[3] = gmul2((f32x2){Sc1[2], Sc1[3]}, (f32x2){g2.z, g2.w});
                acc[2] = __builtin_amdgcn_mfma_f32_16x16x32_bf16(ax, p2.v, acc[2], 0, 0, 0);
                p2.u[0] = gmul2((f32x2){Sd0[0], Sd0[1]}, (f32x2){g4.x, g4.y});
                p2.u[1] = gmul2((f32x2){Sd0[2], Sd0[3]}, (f32x2){g4.z, g4.w});
                p2.u[2] = gmul2((f32x2){Sd1[0], Sd1[1]}, (f32x2){g3.x, g3.y});
                p2.u[3] = gmul2((f32x2){Sd1[2], Sd1[3]}, (f32x2){g3.z, g3.w});
                acc[3] = __builtin_amdgcn_mfma_f32_16x16x32_bf16(ax, p2.v, acc[3], 0, 0, 0);
            }
        }
    }

    // ---------- epilogue: O^T layout: lane (quad,lq): d2 = 4*quad+r, l = lq ----
    if (quad < 2) {
#pragma unroll
        for (int j = 0; j < 4; ++j) {
            const int lA  = wl0 + 16 * j + lq;
            const float sb = sbuf[wb][wseg * 64 + 16 * j + lq];
#pragma unroll
            for (int r = 0; r < 4; ++r) {
                const int ro = baseb + (4 * quad + r) * L + lA;
                out[ro] = acc[j][r] + x2[ro] * sb;
            }
        }
    }
}

extern "C" void kernel_launch(void* const* d_in, const int* in_sizes, int n_in,
                              void* d_out, int out_size, void* d_ws, size_t ws_size,
                              hipStream_t stream) {
    const float* v    = (const float*)d_in[0];
    const float* k    = (const float*)d_in[1];
    const float* bias = (const float*)d_in[2];
    const float* x1   = (const float*)d_in[3];
    const float* x2   = (const float*)d_in[4];
    float* out = (float*)d_out;

    const int D = in_sizes[2];            // 1024
    const int H = D / NHd;                // 128
    const int L = in_sizes[1] / H;        // 2048
    const int B = in_sizes[0] / (D * L);  // 2

    dim3 grid(H, L / 128);
    hyena_mfma23_kernel<<<grid, 256, 0, stream>>>(v, k, bias, x1, x2, out, B, H, L);
}

// Round 14
// 147.033 us; speedup vs baseline: 1.0551x; 1.0551x over previous
//
#include <hip/hip_runtime.h>
#include <stdint.h>

// Multi-head Hyena conv, MFMA flash-attention form, round 24:
//   S^T[m][l] = sum_d1 v[d1,m]*x1[d1,l]       mfma 16x16x16 (K=8 valid)
//   P[l][m]   = S * k[l-m]   (sliding f32x4 gate window, zero => causal)
//   O^T[d2][l] += x2 . P^T                    mfma 16x16x32 (full K=32)
// Round-24: S-MFMA HOIST (pure reorder, zero inst delta). r23's gate
// table regressed -18% (LDS 51.7KB -> occ 30%, tripwire fired; revert).
// r20 = best (70.9us). Ledger: only deletions win; additions lose 1:1;
// plateau cause = per-iter serial chain S-MFMA -> gate -> PV at ~3
// waves/SIMD. This round: hoist ALL 8 S-MFMAs (Sa*..Sd*) to the top of
// the loop body so they issue back-to-back (pipe-filling, latencies
// overlapped) and pair-{0,1} gating runs under pair-{2,3} S completion.
// Cost: +16 live S regs (60 -> ~76-88, vs (256,4) cap 128 -- r13 clean
// at 64). Compiler rarely hoists MFMAs across 30+ dependent VALU ops.
// Tripwire: WRITE>25MB = spill -> revert to r20 verbatim. Neutral =>
// chain is gating-issue-bound -> declare structural plateau at r20.
// Carried (r20): (256,4), 16x16x16 S, dbuf vT/x2T + single barrier per
// chunk, write-late/issue-early v/x2/k stage regs, carried gate file,
// rolling loop, v_pk_mul+v_perm gating.
// Shapes fixed by setup: B=2, D=1024, L=2048, NH=8, H=128.

typedef __attribute__((ext_vector_type(8))) short bf16x8;
typedef __attribute__((ext_vector_type(4))) short bf16x4;
typedef __attribute__((ext_vector_type(4))) float f32x4;
typedef __attribute__((ext_vector_type(2))) float f32x2;

#define NHd  8
#define SC   128     // m superchunk staged in LDS
#define GW   256     // gate window: l-m spans [l0b-s0-127, l0b-s0+127]

static __device__ __forceinline__ uint32_t pkbf(float a, float b) {
    // RNE-ish pack {bf16(a) lo, bf16(b) hi}; +0x8000 rounds (ties away)
    const uint32_t ua = __float_as_uint(a) + 0x8000u;
    const uint32_t ub = __float_as_uint(b) + 0x8000u;
    return __builtin_amdgcn_perm(ub, ua, 0x07060302u);
}

static __device__ __forceinline__ uint32_t pktr(f32x2 p) {
    // truncation pack: upper 16 bits of each f32 -> {lo,hi} bf16 (1 v_perm)
    union { f32x2 f; uint32_t u[2]; } c; c.f = p;
    return __builtin_amdgcn_perm(c.u[1], c.u[0], 0x07060302u);
}

// gate two S values by two k values: v_pk_mul_f32 + v_perm (2 inst)
static __device__ __forceinline__ uint32_t gmul2(f32x2 s, f32x2 g) {
    return pktr(s * g);
}

// S-MFMA: 16x16x16 bf16 (K=8 valid). Same C layout as 16x16x32 family.
static __device__ __forceinline__ f32x4 mfmaS(bf16x4 a, bf16x4 b, f32x4 c) {
#if __has_builtin(__builtin_amdgcn_mfma_f32_16x16x16bf16_1k)
    return __builtin_amdgcn_mfma_f32_16x16x16bf16_1k(a, b, c, 0, 0, 0);
#else
    f32x4 d;
    asm("v_mfma_f32_16x16x16_bf16 %0, %1, %2, %3"
        : "=v"(d) : "v"(a), "v"(b), "v"(c));
    return d;
#endif
}

union U8 { uint32_t u[4]; bf16x8 v; uint4 q; };
union U4 { uint32_t u[2]; bf16x4 v; };

__global__ __launch_bounds__(256, 4) void hyena_mfma24_kernel(
    const float* __restrict__ v, const float* __restrict__ kf,
    const float* __restrict__ bias, const float* __restrict__ x1,
    const float* __restrict__ x2, float* __restrict__ out,
    int B, int H, int L)
{
    __shared__ __align__(16) float4 gwin[2][GW];         // dbuf gate window
    __shared__ __align__(16) ushort vT[2][2][SC][NHd];   // [buf][b][m][d1]
    __shared__ __align__(16) ushort x2T[2][2][NHd][136]; // [buf][b][d2][pi(m)]
    __shared__ float sbuf[2][128];                       // skip gate per (b,l)

    const int tid  = threadIdx.x;
    const int h    = blockIdx.x;
    const int l0b  = ((int)gridDim.y - 1 - (int)blockIdx.y) * 128; // big-l first
    const int nk   = l0b + 128;

    const int lane = tid & 63, wv = tid >> 6;
    const int lq   = lane & 15, quad = lane >> 4;
    const int wb   = wv & 1;                // batch handled by this wave
    const int wseg = wv >> 1;               // which 64-l half of the block
    const int wl0  = l0b + wseg * 64;       // wave's 64-l range start
    const int baseb = (wb * H + h) * NHd * L;

    // ---------- fixed staging coordinates ----------
    const int sb_b   = tid >> 7, sb_row = tid & 127;
    const int sb_bs  = (sb_b * H + h) * NHd * L;
    const float* vp0 = v + sb_bs + sb_row;
    const int sb_d2  = sb_row >> 4, sb_ms = (sb_row & 15) * 8;
    const int sb_G   = sb_ms & ~31;                 // 32-group base
    const int sb_o   = sb_ms & 31;                  // 0,8,16,24
    const int sb_pa  = ((sb_o >> 2) & 3) * 8 + (sb_o >> 4) * 4;
    const float* xp0 = x2 + sb_bs + sb_d2 * L + sb_ms;
    const float* kp  = kf + h * L;
    const int gi0    = l0b - 127 + tid;             // k idx of gwin[tid] @ s0=0

    // ---------- async stage registers (one chunk in flight) ----------
    float  fv0, fv1, fv2, fv3, fv4, fv5, fv6, fv7;  // v column, 8 x d1
    float4 q0, q1;                                   // x2 8-run
    float  kg0 = 0.f, kg1 = 0.f, kg2 = 0.f, kg3 = 0.f; // gate window entry

    auto issue_stage = [&](int s0) {
        const float* vp = vp0 + s0;
        fv0 = vp[0 * L]; fv1 = vp[1 * L]; fv2 = vp[2 * L]; fv3 = vp[3 * L];
        fv4 = vp[4 * L]; fv5 = vp[5 * L]; fv6 = vp[6 * L]; fv7 = vp[7 * L];
        q0 = *(const float4*)(xp0 + s0);
        q1 = *(const float4*)(xp0 + s0 + 4);
        if (tid < GW - 1) {
            const int i = gi0 - s0;
            if (i >= 3) {
                kg0 = kp[i]; kg1 = kp[i - 1]; kg2 = kp[i - 2]; kg3 = kp[i - 3];
            } else {
                kg0 = kg1 = kg2 = kg3 = 0.f;
                if (i >= 0) kg0 = kp[i];
                if (i >= 1) kg1 = kp[i - 1];
                if (i >= 2) kg2 = kp[i - 2];
            }
        }
    };

    // ---------- prologue ----------
    issue_stage(0);   // chunk-0 loads fly under xf/sbuf build below

    // xf fragments (S-MFMA B operand, 16x16x16: k=4*(lane>>4)+i) for 4
    // l-subtiles. Quads 0-1 carry d1 = 4*quad+t; quads 2-3 zero.
    bf16x4 xf[4] = {};
    if (quad < 2) {
#pragma unroll
        for (int j = 0; j < 4; ++j) {
            float a0[4];
#pragma unroll
            for (int t = 0; t < 4; ++t)
                a0[t] = x1[baseb + (4 * quad + t) * L + wl0 + 16 * j + lq];
            U4 u0;
            u0.u[0] = pkbf(a0[0], a0[1]);
            u0.u[1] = pkbf(a0[2], a0[3]);
            xf[j] = u0.v;
        }
    }

    // skip-term gate, both b, 128 l (all 256 threads)
    {
        const int bb = tid >> 7, l = tid & 127;
        const int bs = (bb * H + h) * NHd * L;
        float s = 0.f;
#pragma unroll
        for (int d1 = 0; d1 < NHd; ++d1)
            s += bias[h * NHd + d1] * x1[bs + d1 * L + l0b + l]
                                    * v [bs + d1 * L + l0b + l];
        sbuf[bb][l] = s;
    }

    f32x4 acc[4];
#pragma unroll
    for (int j = 0; j < 4; ++j) acc[j] = (f32x4){0.f, 0.f, 0.f, 0.f};

    const int wlmax = wl0 + 63;
    // gate window coordinate (s0-independent): e = ebase - c
    const int ebase = 127 + wseg * 64 + lq - 4 * quad;

    bool gfirst = true;
    float4 g0, g1, g2, g3, g4;   // 5-deep gate file; carries across s0 too

    for (int s0 = 0, n = 0; s0 < nk; s0 += SC, ++n) {
        const int p = n & 1;

        // ---- write-late: stage regs (chunk n's data) -> buf p ----
        // WAR-safe: all waves passed barrier n-1, which follows their
        // compute n-2 (the last reader of buf p). Concurrent compute n-1
        // reads buf p^1.
        *(uint4*)&vT[p][sb_b][sb_row][0] = make_uint4(
            pkbf(fv0, fv1), pkbf(fv2, fv3), pkbf(fv4, fv5), pkbf(fv6, fv7));
        *(uint2*)&x2T[p][sb_b][sb_d2][sb_G + sb_pa] =
            make_uint2(pkbf(q0.x, q0.y), pkbf(q0.z, q0.w));
        *(uint2*)&x2T[p][sb_b][sb_d2][sb_G + sb_pa + 8] =
            make_uint2(pkbf(q1.x, q1.y), pkbf(q1.z, q1.w));
        // gwin[p][e] = {k[i],k[i-1],k[i-2],k[i-3]}, i = l0b-s0-127+e;
        // entry 255 never read (max read index 254) -> skip.
        if (tid < GW - 1)
            gwin[p][tid] = make_float4(kg0, kg1, kg2, kg3);

        // ---- issue-early: next chunk's global loads fly under compute ----
        if (s0 + SC < nk) issue_stage(s0 + SC);

        // ---- single barrier: staging visible; global loads NOT drained ----
        asm volatile("s_waitcnt lgkmcnt(0)" ::: "memory");
        __builtin_amdgcn_s_barrier();

        // wave-uniform trip count, multiple of 32 (wseg0: 64 at diagonal)
        const int cmax = min(SC, wlmax - s0 + 1);
        for (int c = 0; c < cmax; c += 32) {
            const int e = ebase - c;

            // ---- loads first (independent) ----
            // A frag (16x16x16): row=lane&15, k=4*(lane>>4)+i -> quads 0-1
            // read d1 = 4*quad..4*quad+3 (8B each); quads 2-3 zero.
            bf16x4 av0 = {}, av1 = {};
            if (quad < 2) {
                av0 = *(const bf16x4*)&vT[p][wb][c + lq][quad * 4];
                av1 = *(const bf16x4*)&vT[p][wb][c + 16 + lq][quad * 4];
            }
            // gate file: subtile j: lo = g(e+16j), hi = g(e+16j-16)
            if (gfirst) {
                g4 = *(const float4*)&gwin[p][e + 48];
                g3 = *(const float4*)&gwin[p][e + 32];
                g2 = *(const float4*)&gwin[p][e + 16];
                gfirst = false;
            } else { g4 = g2; g3 = g1; g2 = g0; }
            g1 = *(const float4*)&gwin[p][e];
            g0 = *(const float4*)&gwin[p][e - 16];
            const bf16x8 ax = *(const bf16x8*)&x2T[p][wb][lq & 7][c + 8 * quad];

            const f32x4 Z = {0.f, 0.f, 0.f, 0.f};

            // ---- ALL 8 S-MFMAs issued together (round-24 hoist): they
            // are mutually independent, share av0/av1, and fill the
            // matrix pipe; gating of pair {0,1} below overlaps the tail
            // latency of pair {2,3}'s S results. ----
            const f32x4 Sa0 = mfmaS(av0, xf[0], Z);
            const f32x4 Sa1 = mfmaS(av1, xf[0], Z);
            const f32x4 Sb0 = mfmaS(av0, xf[1], Z);
            const f32x4 Sb1 = mfmaS(av1, xf[1], Z);
            const f32x4 Sc0 = mfmaS(av0, xf[2], Z);
            const f32x4 Sc1 = mfmaS(av1, xf[2], Z);
            const f32x4 Sd0 = mfmaS(av0, xf[3], Z);
            const f32x4 Sd1 = mfmaS(av1, xf[3], Z);

            // ---- gating + PV, pair 0,1 ----
            {
                U8 p2;
                p2.u[0] = gmul2((f32x2){Sa0[0], Sa0[1]}, (f32x2){g1.x, g1.y});
                p2.u[1] = gmul2((f32x2){Sa0[2], Sa0[3]}, (f32x2){g1.z, g1.w});
                p2.u[2] = gmul2((f32x2){Sa1[0], Sa1[1]}, (f32x2){g0.x, g0.y});
                p2.u[3] = gmul2((f32x2){Sa1[2], Sa1[3]}, (f32x2){g0.z, g0.w});
                acc[0] = __builtin_amdgcn_mfma_f32_16x16x32_bf16(ax, p2.v, acc[0], 0, 0, 0);
                p2.u[0] = gmul2((f32x2){Sb0[0], Sb0[1]}, (f32x2){g2.x, g2.y});
                p2.u[1] = gmul2((f32x2){Sb0[2], Sb0[3]}, (f32x2){g2.z, g2.w});
                p2.u[2] = gmul2((f32x2){Sb1[0], Sb1[1]}, (f32x2){g1.x, g1.y});
                p2.u[3] = gmul2((f32x2){Sb1[2], Sb1[3]}, (f32x2){g1.z, g1.w});
                acc[1] = __builtin_amdgcn_mfma_f32_16x16x32_bf16(ax, p2.v, acc[1], 0, 0, 0);
            }
            // ---- gating + PV, pair 2,3 ----
            {
                U8 p2;
                p2.u[0] = gmul2((f32x2){Sc0[0], Sc0[1]}, (f32x2){g3.x, g3.y});
                p2.u[1] = gmul2((f32x2){Sc0[2], Sc0[3]}, (f32x2){g3.z, g3.w});
                p2.u[2] = gmul2((f32x2){Sc1[0], Sc1[1]}, (f32x2){g2.x, g2.y});
                p2.u[3] = gmul2((f32x2){Sc1[2], Sc1[3]}, (f32x2){g2.z, g2.w});
                acc[2] = __builtin_amdgcn_mfma_f32_16x16x32_bf16(ax, p2.v, acc[2], 0, 0, 0);
                p2.u[0] = gmul2((f32x2){Sd0[0], Sd0[1]}, (f32x2){g4.x, g4.y});
                p2.u[1] = gmul2((f32x2){Sd0[2], Sd0[3]}, (f32x2){g4.z, g4.w});
                p2.u[2] = gmul2((f32x2){Sd1[0], Sd1[1]}, (f32x2){g3.x, g3.y});
                p2.u[3] = gmul2((f32x2){Sd1[2], Sd1[3]}, (f32x2){g3.z, g3.w});
                acc[3] = __builtin_amdgcn_mfma_f32_16x16x32_bf16(ax, p2.v, acc[3], 0, 0, 0);
            }
        }
    }

    // ---------- epilogue: O^T layout: lane (quad,lq): d2 = 4*quad+r, l = lq ----
    if (quad < 2) {
#pragma unroll
        for (int j = 0; j < 4; ++j) {
            const int lA  = wl0 + 16 * j + lq;
            const float sb = sbuf[wb][wseg * 64 + 16 * j + lq];
#pragma unroll
            for (int r = 0; r < 4; ++r) {
                const int ro = baseb + (4 * quad + r) * L + lA;
                out[ro] = acc[j][r] + x2[ro] * sb;
            }
        }
    }
}

extern "C" void kernel_launch(void* const* d_in, const int* in_sizes, int n_in,
                              void* d_out, int out_size, void* d_ws, size_t ws_size,
                              hipStream_t stream) {
    const float* v    = (const float*)d_in[0];
    const float* k    = (const float*)d_in[1];
    const float* bias = (const float*)d_in[2];
    const float* x1   = (const float*)d_in[3];
    const float* x2   = (const float*)d_in[4];
    float* out = (float*)d_out;

    const int D = in_sizes[2];            // 1024
    const int H = D / NHd;                // 128
    const int L = in_sizes[1] / H;        // 2048
    const int B = in_sizes[0] / (D * L);  // 2

    dim3 grid(H, L / 128);
    hyena_mfma24_kernel<<<grid, 256, 0, stream>>>(v, k, bias, x1, x2, out, B, H, L);
}

// Round 15
// 144.235 us; speedup vs baseline: 1.0756x; 1.0194x over previous
//
#include <hip/hip_runtime.h>
#include <stdint.h>

// Multi-head Hyena conv, MFMA flash-attention form, round 25:
//   S^T[m][l] = sum_d1 v[d1,m]*x1[d1,l]       mfma 16x16x16 (K=8 valid)
//   P[l][m]   = S * k[l-m]   (sliding f32x4 gate window, zero => causal)
//   O^T[d2][l] += x2 . P^T                    mfma 16x16x32 (full K=32)
// Round-25: r20 base (r24 hoist reverted: WRITE 26.5MB spill tripwire,
// -14%) + GWIN XOR-SWIZZLE (T2) with ZERO inner-loop instruction delta.
// Counter evidence: SQ_LDS_BANK_CONFLICT 2.72M cyc/dispatch (~6% wall +
// latency on the g->gating chain). gwin reads: bank-group = e&7, lane
// span 28 => 3-4-way; writes: tid&7 => ~4-way. Swizzle: byte offset
// (e<<4) ^ ((e&24)<<2) -- XOR byte bits 5,6 with e bits 3,4; entries 8
// and 16 apart disperse; 16B alignment kept. e steps by -32 per iter =>
// e&24 invariant, and c<<4 (bits>=9) commutes with the XOR (bits 5,6):
// ((ebase<<4)^S)-(c<<4) == (((ebase-c)<<4)^S) EXACTLY -> swizzled base
// pointer hoisted per chunk; loop body addressing cost identical to r20.
// Write side: swizzle the thread-constant tid offset. vT (2-way, free)
// and x2T/ax untouched this round.
// Predict: conflicts 2.72M -> ~1.2-1.7M; dur 70.9 -> 66-69us if g-read
// serialization is on the chain; neutral => conflicts hidden, plateau.
// Tripwire: WRITE>25MB = spill -> revert to r20 verbatim.
// Carried (r20): (256,4), 16x16x16 S, dbuf vT/x2T + single barrier per
// chunk, write-late/issue-early v/x2/k stage regs, carried gate file,
// rolling loop, paired subtile structure, v_pk_mul+v_perm gating.
// Shapes fixed by setup: B=2, D=1024, L=2048, NH=8, H=128.

typedef __attribute__((ext_vector_type(8))) short bf16x8;
typedef __attribute__((ext_vector_type(4))) short bf16x4;
typedef __attribute__((ext_vector_type(4))) float f32x4;
typedef __attribute__((ext_vector_type(2))) float f32x2;

#define NHd  8
#define SC   128     // m superchunk staged in LDS
#define GW   256     // gate window: l-m spans [l0b-s0-127, l0b-s0+127]

// gwin swizzled byte offset for entry index E (16B granules):
//   XOR byte bits 5,6 with E bits 3,4 -> breaks e%8 bank aliasing.
#define GSWZ(E) ((((E) << 4)) ^ ((((E) & 24)) << 2))

static __device__ __forceinline__ uint32_t pkbf(float a, float b) {
    // RNE-ish pack {bf16(a) lo, bf16(b) hi}; +0x8000 rounds (ties away)
    const uint32_t ua = __float_as_uint(a) + 0x8000u;
    const uint32_t ub = __float_as_uint(b) + 0x8000u;
    return __builtin_amdgcn_perm(ub, ua, 0x07060302u);
}

static __device__ __forceinline__ uint32_t pktr(f32x2 p) {
    // truncation pack: upper 16 bits of each f32 -> {lo,hi} bf16 (1 v_perm)
    union { f32x2 f; uint32_t u[2]; } c; c.f = p;
    return __builtin_amdgcn_perm(c.u[1], c.u[0], 0x07060302u);
}

// gate two S values by two k values: v_pk_mul_f32 + v_perm (2 inst)
static __device__ __forceinline__ uint32_t gmul2(f32x2 s, f32x2 g) {
    return pktr(s * g);
}

// S-MFMA: 16x16x16 bf16 (K=8 valid). Same C layout as 16x16x32 family.
static __device__ __forceinline__ f32x4 mfmaS(bf16x4 a, bf16x4 b, f32x4 c) {
#if __has_builtin(__builtin_amdgcn_mfma_f32_16x16x16bf16_1k)
    return __builtin_amdgcn_mfma_f32_16x16x16bf16_1k(a, b, c, 0, 0, 0);
#else
    f32x4 d;
    asm("v_mfma_f32_16x16x16_bf16 %0, %1, %2, %3"
        : "=v"(d) : "v"(a), "v"(b), "v"(c));
    return d;
#endif
}

union U8 { uint32_t u[4]; bf16x8 v; uint4 q; };
union U4 { uint32_t u[2]; bf16x4 v; };

__global__ __launch_bounds__(256, 4) void hyena_mfma25_kernel(
    const float* __restrict__ v, const float* __restrict__ kf,
    const float* __restrict__ bias, const float* __restrict__ x1,
    const float* __restrict__ x2, float* __restrict__ out,
    int B, int H, int L)
{
    __shared__ __align__(16) float4 gwin[2][GW];         // dbuf gate window
    __shared__ __align__(16) ushort vT[2][2][SC][NHd];   // [buf][b][m][d1]
    __shared__ __align__(16) ushort x2T[2][2][NHd][136]; // [buf][b][d2][pi(m)]
    __shared__ float sbuf[2][128];                       // skip gate per (b,l)

    const int tid  = threadIdx.x;
    const int h    = blockIdx.x;
    const int l0b  = ((int)gridDim.y - 1 - (int)blockIdx.y) * 128; // big-l first
    const int nk   = l0b + 128;

    const int lane = tid & 63, wv = tid >> 6;
    const int lq   = lane & 15, quad = lane >> 4;
    const int wb   = wv & 1;                // batch handled by this wave
    const int wseg = wv >> 1;               // which 64-l half of the block
    const int wl0  = l0b + wseg * 64;       // wave's 64-l range start
    const int baseb = (wb * H + h) * NHd * L;

    // ---------- fixed staging coordinates ----------
    const int sb_b   = tid >> 7, sb_row = tid & 127;
    const int sb_bs  = (sb_b * H + h) * NHd * L;
    const float* vp0 = v + sb_bs + sb_row;
    const int sb_d2  = sb_row >> 4, sb_ms = (sb_row & 15) * 8;
    const int sb_G   = sb_ms & ~31;                 // 32-group base
    const int sb_o   = sb_ms & 31;                  // 0,8,16,24
    const int sb_pa  = ((sb_o >> 2) & 3) * 8 + (sb_o >> 4) * 4;
    const float* xp0 = x2 + sb_bs + sb_d2 * L + sb_ms;
    const float* kp  = kf + h * L;
    const int gi0    = l0b - 127 + tid;             // k idx of gwin[tid] @ s0=0
    const int gwoff  = GSWZ(tid);                   // swizzled write offset

    // ---------- async stage registers (one chunk in flight) ----------
    float  fv0, fv1, fv2, fv3, fv4, fv5, fv6, fv7;  // v column, 8 x d1
    float4 q0, q1;                                   // x2 8-run
    float  kg0 = 0.f, kg1 = 0.f, kg2 = 0.f, kg3 = 0.f; // gate window entry

    auto issue_stage = [&](int s0) {
        const float* vp = vp0 + s0;
        fv0 = vp[0 * L]; fv1 = vp[1 * L]; fv2 = vp[2 * L]; fv3 = vp[3 * L];
        fv4 = vp[4 * L]; fv5 = vp[5 * L]; fv6 = vp[6 * L]; fv7 = vp[7 * L];
        q0 = *(const float4*)(xp0 + s0);
        q1 = *(const float4*)(xp0 + s0 + 4);
        if (tid < GW - 1) {
            const int i = gi0 - s0;
            if (i >= 3) {
                kg0 = kp[i]; kg1 = kp[i - 1]; kg2 = kp[i - 2]; kg3 = kp[i - 3];
            } else {
                kg0 = kg1 = kg2 = kg3 = 0.f;
                if (i >= 0) kg0 = kp[i];
                if (i >= 1) kg1 = kp[i - 1];
                if (i >= 2) kg2 = kp[i - 2];
            }
        }
    };

    // ---------- prologue ----------
    issue_stage(0);   // chunk-0 loads fly under xf/sbuf build below

    // xf fragments (S-MFMA B operand, 16x16x16: k=4*(lane>>4)+i) for 4
    // l-subtiles. Quads 0-1 carry d1 = 4*quad+t; quads 2-3 zero.
    bf16x4 xf[4] = {};
    if (quad < 2) {
#pragma unroll
        for (int j = 0; j < 4; ++j) {
            float a0[4];
#pragma unroll
            for (int t = 0; t < 4; ++t)
                a0[t] = x1[baseb + (4 * quad + t) * L + wl0 + 16 * j + lq];
            U4 u0;
            u0.u[0] = pkbf(a0[0], a0[1]);
            u0.u[1] = pkbf(a0[2], a0[3]);
            xf[j] = u0.v;
        }
    }

    // skip-term gate, both b, 128 l (all 256 threads)
    {
        const int bb = tid >> 7, l = tid & 127;
        const int bs = (bb * H + h) * NHd * L;
        float s = 0.f;
#pragma unroll
        for (int d1 = 0; d1 < NHd; ++d1)
            s += bias[h * NHd + d1] * x1[bs + d1 * L + l0b + l]
                                    * v [bs + d1 * L + l0b + l];
        sbuf[bb][l] = s;
    }

    f32x4 acc[4];
#pragma unroll
    for (int j = 0; j < 4; ++j) acc[j] = (f32x4){0.f, 0.f, 0.f, 0.f};

    const int wlmax = wl0 + 63;
    // gate window coordinate (s0-independent): e = ebase - c
    const int ebase = 127 + wseg * 64 + lq - 4 * quad;
    // swizzled-base byte offsets for the two read streams (e and e-16):
    // (e&24) and ((e-16)&24) are invariant under c (multiple of 32), and
    // the XOR (bits 5,6) commutes with subtracting c<<4 (bits >= 9).
    const int gro1 = GSWZ(ebase);
    const int gro0 = GSWZ(ebase - 16);

    bool gfirst = true;
    float4 g0, g1, g2, g3, g4;   // 5-deep gate file; carries across s0 too

    for (int s0 = 0, n = 0; s0 < nk; s0 += SC, ++n) {
        const int p = n & 1;

        // ---- write-late: stage regs (chunk n's data) -> buf p ----
        // WAR-safe: all waves passed barrier n-1, which follows their
        // compute n-2 (the last reader of buf p). Concurrent compute n-1
        // reads buf p^1.
        *(uint4*)&vT[p][sb_b][sb_row][0] = make_uint4(
            pkbf(fv0, fv1), pkbf(fv2, fv3), pkbf(fv4, fv5), pkbf(fv6, fv7));
        *(uint2*)&x2T[p][sb_b][sb_d2][sb_G + sb_pa] =
            make_uint2(pkbf(q0.x, q0.y), pkbf(q0.z, q0.w));
        *(uint2*)&x2T[p][sb_b][sb_d2][sb_G + sb_pa + 8] =
            make_uint2(pkbf(q1.x, q1.y), pkbf(q1.z, q1.w));
        // gwin[p] swizzled write: entry tid -> byte GSWZ(tid); entry 255
        // never read (max read index 254) -> skip.
        if (tid < GW - 1)
            *(float4*)((char*)gwin[p] + gwoff) = make_float4(kg0, kg1, kg2, kg3);

        // ---- issue-early: next chunk's global loads fly under compute ----
        if (s0 + SC < nk) issue_stage(s0 + SC);

        // ---- single barrier: staging visible; global loads NOT drained ----
        asm volatile("s_waitcnt lgkmcnt(0)" ::: "memory");
        __builtin_amdgcn_s_barrier();

        // swizzled read base pointers for this chunk's buffer
        const char* gB  = (const char*)gwin[p];
        const char* gp1 = gB + gro1;
        const char* gp0 = gB + gro0;

        // wave-uniform trip count, multiple of 32 (wseg0: 64 at diagonal)
        const int cmax = min(SC, wlmax - s0 + 1);
        for (int c = 0; c < cmax; c += 32) {
            const int e = ebase - c;

            // ---- loads first (independent) ----
            // A frag (16x16x16): row=lane&15, k=4*(lane>>4)+i -> quads 0-1
            // read d1 = 4*quad..4*quad+3 (8B each); quads 2-3 zero.
            bf16x4 av0 = {}, av1 = {};
            if (quad < 2) {
                av0 = *(const bf16x4*)&vT[p][wb][c + lq][quad * 4];
                av1 = *(const bf16x4*)&vT[p][wb][c + 16 + lq][quad * 4];
            }
            // gate file: subtile j: lo = g(e+16j), hi = g(e+16j-16).
            // Reads use swizzled offsets; (base^S) - (c<<4) == swz(e) exactly.
            if (gfirst) {
                g4 = *(const float4*)(gB + GSWZ(e + 48));
                g3 = *(const float4*)(gB + GSWZ(e + 32));
                g2 = *(const float4*)(gB + GSWZ(e + 16));
                gfirst = false;
            } else { g4 = g2; g3 = g1; g2 = g0; }
            g1 = *(const float4*)(gp1 - (c << 4));
            g0 = *(const float4*)(gp0 - (c << 4));
            const bf16x8 ax = *(const bf16x8*)&x2T[p][wb][lq & 7][c + 8 * quad];

            const f32x4 Z = {0.f, 0.f, 0.f, 0.f};
            // ---- subtile pair 0,1 ----
            {
                const f32x4 Sa0 = mfmaS(av0, xf[0], Z);
                const f32x4 Sa1 = mfmaS(av1, xf[0], Z);
                const f32x4 Sb0 = mfmaS(av0, xf[1], Z);
                const f32x4 Sb1 = mfmaS(av1, xf[1], Z);
                U8 p2;
                p2.u[0] = gmul2((f32x2){Sa0[0], Sa0[1]}, (f32x2){g1.x, g1.y});
                p2.u[1] = gmul2((f32x2){Sa0[2], Sa0[3]}, (f32x2){g1.z, g1.w});
                p2.u[2] = gmul2((f32x2){Sa1[0], Sa1[1]}, (f32x2){g0.x, g0.y});
                p2.u[3] = gmul2((f32x2){Sa1[2], Sa1[3]}, (f32x2){g0.z, g0.w});
                acc[0] = __builtin_amdgcn_mfma_f32_16x16x32_bf16(ax, p2.v, acc[0], 0, 0, 0);
                p2.u[0] = gmul2((f32x2){Sb0[0], Sb0[1]}, (f32x2){g2.x, g2.y});
                p2.u[1] = gmul2((f32x2){Sb0[2], Sb0[3]}, (f32x2){g2.z, g2.w});
                p2.u[2] = gmul2((f32x2){Sb1[0], Sb1[1]}, (f32x2){g1.x, g1.y});
                p2.u[3] = gmul2((f32x2){Sb1[2], Sb1[3]}, (f32x2){g1.z, g1.w});
                acc[1] = __builtin_amdgcn_mfma_f32_16x16x32_bf16(ax, p2.v, acc[1], 0, 0, 0);
            }
            // ---- subtile pair 2,3 ----
            {
                const f32x4 Sc0 = mfmaS(av0, xf[2], Z);
                const f32x4 Sc1 = mfmaS(av1, xf[2], Z);
                const f32x4 Sd0 = mfmaS(av0, xf[3], Z);
                const f32x4 Sd1 = mfmaS(av1, xf[3], Z);
                U8 p2;
                p2.u[0] = gmul2((f32x2){Sc0[0], Sc0[1]}, (f32x2){g3.x, g3.y});
                p2.u[1] = gmul2((f32x2){Sc0[2], Sc0[3]}, (f32x2){g3.z, g3.w});
                p2.u[2] = gmul2((f32x2){Sc1[0], Sc1[1]}, (f32x2){g2.x, g2.y});
                p2.u[3] = gmul2((f32x2){Sc1[2], Sc1[3]}, (f32x2){g2.z, g2.w});
                acc[2] = __builtin_amdgcn_mfma_f32_16x16x32_bf16(ax, p2.v, acc[2], 0, 0, 0);
                p2.u[0] = gmul2((f32x2){Sd0[0], Sd0[1]}, (f32x2){g4.x, g4.y});
                p2.u[1] = gmul2((f32x2){Sd0[2], Sd0[3]}, (f32x2){g4.z, g4.w});
                p2.u[2] = gmul2((f32x2){Sd1[0], Sd1[1]}, (f32x2){g3.x, g3.y});
                p2.u[3] = gmul2((f32x2){Sd1[2], Sd1[3]}, (f32x2){g3.z, g3.w});
                acc[3] = __builtin_amdgcn_mfma_f32_16x16x32_bf16(ax, p2.v, acc[3], 0, 0, 0);
            }
        }
    }

    // ---------- epilogue: O^T layout: lane (quad,lq): d2 = 4*quad+r, l = lq ----
    if (quad < 2) {
#pragma unroll
        for (int j = 0; j < 4; ++j) {
            const int lA  = wl0 + 16 * j + lq;
            const float sb = sbuf[wb][wseg * 64 + 16 * j + lq];
#pragma unroll
            for (int r = 0; r < 4; ++r) {
                const int ro = baseb + (4 * quad + r) * L + lA;
                out[ro] = acc[j][r] + x2[ro] * sb;
            }
        }
    }
}

extern "C" void kernel_launch(void* const* d_in, const int* in_sizes, int n_in,
                              void* d_out, int out_size, void* d_ws, size_t ws_size,
                              hipStream_t stream) {
    const float* v    = (const float*)d_in[0];
    const float* k    = (const float*)d_in[1];
    const float* bias = (const float*)d_in[2];
    const float* x1   = (const float*)d_in[3];
    const float* x2   = (const float*)d_in[4];
    float* out = (float*)d_out;

    const int D = in_sizes[2];            // 1024
    const int H = D / NHd;                // 128
    const int L = in_sizes[1] / H;        // 2048
    const int B = in_sizes[0] / (D * L);  // 2

    dim3 grid(H, L / 128);
    hyena_mfma25_kernel<<<grid, 256, 0, stream>>>(v, k, bias, x1, x2, out, B, H, L);
}